// Round 9
// baseline (359.446 us; speedup 1.0000x reference)
//
#include <hip/hip_runtime.h>
#include <cstdint>

// GNN: 2-layer GraphSAGE (mean aggr, L2-normalize) + BatchNorm(train) + ReLU.
// N=100000 nodes, E=800000 edges, C: 128 -> 128 -> 47.
//
// Round 9: gather1 FUSED into gemm1. Phase A: each block aggregates its own
// 128 rows (16-lane groups, 4-edge unroll) into an LDS tile (stride 132
// shorts -> conflict-free MFMA A-frag reads). Phase B: K-loop reads agg half
// from LDS (kt<4, stages weights only) and x half from global (kt>=4).
// 3 blocks/CU resident -> one block's latency-bound gather overlaps another
// block's MFMA (m114). Kills the 51 MB aggb round-trip and one launch.
// Also: gather2 8-edge unroll; stats zeroing folded into k_prep.
// CSR build: bucketed counting sort (R8). GEMMs: bf16 MFMA 16x16x32
// (fp32 VALU ceiling measured 111 TF in R5; MFMA bypasses it).

typedef __attribute__((ext_vector_type(8))) short s8v;
typedef __attribute__((ext_vector_type(4))) float fx4;

#define CSR_CHUNK 8192
#define CSR_SH 8            // 256 nodes per bucket
#define CSR_NBPAD 512       // padded bucket count (NB = ceil(n/256) = 391)
#define CSR_BUFCAP 3072     // LDS srcbuf cap per bucket (mean 2046, +20 sigma)

static __device__ __forceinline__ float bf2f(unsigned short h) {
    union { unsigned int u; float f; } c; c.u = (unsigned int)h << 16; return c.f;
}
static __device__ __forceinline__ unsigned short f2bf(float f) {
    union { float f; unsigned int u; } c; c.f = f;
    unsigned int u = c.u;
    return (unsigned short)((u + 0x7FFF + ((u >> 16) & 1)) >> 16);   // RNE
}

static __device__ __forceinline__ float warp_sum64(float v) {
    #pragma unroll
    for (int off = 32; off > 0; off >>= 1) v += __shfl_xor(v, off, 64);
    return v;
}

// ---- merged prep: x->bf16 cast | weight bf16 transposes | stats zero.
__global__ __launch_bounds__(256) void k_prep(
        const float* __restrict__ x, const float* __restrict__ w1l,
        const float* __restrict__ w1r, const float* __restrict__ w2l,
        const float* __restrict__ w2r,
        unsigned short* __restrict__ xb, unsigned short* __restrict__ wB1,
        unsigned short* __restrict__ wB2p, float* __restrict__ stats, int n) {
    int idx = blockIdx.x * 256 + threadIdx.x;
    int nx = n * 16;
    if (idx < nx) {
        float4 a = ((const float4*)x)[idx * 2];
        float4 b = ((const float4*)x)[idx * 2 + 1];
        union { s8v v; unsigned short u[8]; } o;
        o.u[0] = f2bf(a.x); o.u[1] = f2bf(a.y); o.u[2] = f2bf(a.z); o.u[3] = f2bf(a.w);
        o.u[4] = f2bf(b.x); o.u[5] = f2bf(b.y); o.u[6] = f2bf(b.z); o.u[7] = f2bf(b.w);
        ((s8v*)xb)[idx] = o.v;
        return;
    }
    idx -= nx;
    if (idx < 32768) {
        int j = idx >> 8, k = idx & 255;
        float v = (k < 128) ? w1l[j * 128 + k] : w1r[j * 128 + (k - 128)];
        wB1[idx] = f2bf(v);
        return;
    }
    idx -= 32768;
    if (idx < 16384) {
        int j = idx >> 7, k = idx & 127;
        float v = 0.f;
        if (j < 47)      v = w2l[j * 128 + k];
        else if (j < 94) v = w2r[(j - 47) * 128 + k];
        wB2p[idx] = f2bf(v);
        return;
    }
    idx -= 16384;
    if (idx < 256) stats[idx] = 0.f;
}

// ---- CSR build: bucketed counting sort -------------------------------
__global__ __launch_bounds__(256) void k_bcount(
        const int* __restrict__ ei, int* __restrict__ counts, int nE) {
    __shared__ int hist[CSR_NBPAD];
    int t = threadIdx.x;
    hist[t] = 0; hist[t + 256] = 0;
    __syncthreads();
    int e0 = blockIdx.x * CSR_CHUNK;
    int e1 = min(e0 + CSR_CHUNK, nE);
    for (int e = e0 + t; e < e1; e += 256)
        atomicAdd(&hist[ei[nE + e] >> CSR_SH], 1);
    __syncthreads();
    counts[blockIdx.x * CSR_NBPAD + t] = hist[t];
    counts[blockIdx.x * CSR_NBPAD + t + 256] = hist[t + 256];
}

__global__ __launch_bounds__(256) void k_bmeta(
        int* __restrict__ counts, int* __restrict__ bucketStart,
        int nE, int nCh, int NB) {
    __shared__ int tot[CSR_NBPAD], sh[256], bs[CSR_NBPAD];
    int t = threadIdx.x;
    for (int b = t; b < CSR_NBPAD; b += 256) {
        int s = 0;
        for (int c = 0; c < nCh; ++c) s += counts[c * CSR_NBPAD + b];
        tot[b] = s;
    }
    __syncthreads();
    int pairSum = tot[2 * t] + tot[2 * t + 1];
    sh[t] = pairSum;
    __syncthreads();
    for (int off = 1; off < 256; off <<= 1) {
        int add = (t >= off) ? sh[t - off] : 0;
        __syncthreads();
        sh[t] += add;
        __syncthreads();
    }
    int excl = sh[t] - pairSum;
    bs[2 * t] = excl;
    bs[2 * t + 1] = excl + tot[2 * t];
    __syncthreads();
    for (int b = t; b <= NB; b += 256) bucketStart[b] = bs[b];
    for (int b = t; b < CSR_NBPAD; b += 256) {
        int run = bs[b];
        for (int c = 0; c < nCh; ++c) {
            int v = counts[c * CSR_NBPAD + b];
            counts[c * CSR_NBPAD + b] = run;
            run += v;
        }
    }
}

__global__ __launch_bounds__(256) void k_bfill(
        const int* __restrict__ ei, const int* __restrict__ counts,
        int* __restrict__ pairs, int nE) {
    __shared__ int cur[CSR_NBPAD];
    int t = threadIdx.x;
    cur[t] = counts[blockIdx.x * CSR_NBPAD + t];
    cur[t + 256] = counts[blockIdx.x * CSR_NBPAD + t + 256];
    __syncthreads();
    int e0 = blockIdx.x * CSR_CHUNK;
    int e1 = min(e0 + CSR_CHUNK, nE);
    for (int e = e0 + t; e < e1; e += 256) {
        int s = ei[e];
        int d = ei[nE + e];
        int p = atomicAdd(&cur[d >> CSR_SH], 1);
        pairs[p] = (s << 8) | (d & 255);
    }
}

__global__ __launch_bounds__(256) void k_csr(
        const int* __restrict__ pairs, const int* __restrict__ bucketStart,
        int* __restrict__ deg, int* __restrict__ rowStart,
        int* __restrict__ srcIdx, int n) {
    __shared__ int cnt[256], scn[256], cur[256];
    __shared__ int buf[CSR_BUFCAP];
    int t = threadIdx.x;
    int bkt = blockIdx.x;
    int eBeg = bucketStart[bkt], eEnd = bucketStart[bkt + 1];
    int node0 = bkt << CSR_SH;
    cnt[t] = 0;
    __syncthreads();
    for (int e = eBeg + t; e < eEnd; e += 256)
        atomicAdd(&cnt[pairs[e] & 255], 1);
    __syncthreads();
    int myc = cnt[t];
    scn[t] = myc;
    __syncthreads();
    for (int off = 1; off < 256; off <<= 1) {
        int add = (t >= off) ? scn[t - off] : 0;
        __syncthreads();
        scn[t] += add;
        __syncthreads();
    }
    int excl = scn[t] - myc;
    cur[t] = excl;
    int node = node0 + t;
    if (node < n) { deg[node] = myc; rowStart[node] = eBeg + excl; }
    __syncthreads();
    for (int e = eBeg + t; e < eEnd; e += 256) {
        int pk = pairs[e];
        int p = atomicAdd(&cur[pk & 255], 1);
        int src = pk >> 8;
        if (p < CSR_BUFCAP) buf[p] = src;
        else srcIdx[eBeg + p] = src;   // statistically never at this size
    }
    __syncthreads();
    int m = min(eEnd - eBeg, CSR_BUFCAP);
    for (int i = t; i < m; i += 256) srcIdx[eBeg + i] = buf[i];
}

// ---- GEMM1 (bf16 MFMA) with FUSED layer-1 gather.
// Phase A: block aggregates its 128 rows into LDS aggs (mean of neighbors).
// Phase B: s1 = L2norm_rows( agg @ w1l^T + b1l + x @ w1r^T ), K=256
// (kt<4: A-frags from aggs LDS; kt>=4: x staged from global).
// Also accumulates per-channel sum/sumsq of s1 into stats.
__global__ __launch_bounds__(256, 3) void k_gemm1(
        const unsigned short* __restrict__ xb, const unsigned short* __restrict__ wB1,
        const float* __restrict__ b1l, const int* __restrict__ rowStart,
        const int* __restrict__ deg, const int* __restrict__ srcIdx,
        unsigned short* __restrict__ s1b, float* __restrict__ stats, int n) {
    __shared__ __align__(16) unsigned short aggs[128 * 132];  // [row][k] stride 132
    __shared__ __align__(16) unsigned short xs[128 * 40];     // [row][k] stride 40
    __shared__ __align__(16) unsigned short ws[128 * 40];     // [j][k]   stride 40
    int t = threadIdx.x;
    int w = t >> 6, L = t & 63;
    int q = L >> 4, lm = L & 15;
    int wr0 = (w >> 1) * 64;     // wave row base
    int wc0 = (w & 1) * 64;      // wave col base
    int r0 = blockIdx.x * 128;

    // ---- phase A: aggregate 128 rows (16-lane groups, 8 nodes each)
    {
        int grp = t >> 4, qq = t & 15;
        #pragma unroll 1
        for (int ni = 0; ni < 8; ++ni) {
            int nd = ni * 16 + grp;
            int gr = r0 + nd;
            int beg = 0, d = 0;
            if (gr < n) { beg = rowStart[gr]; d = deg[gr]; }
            int end = beg + d;
            float a0[8] = {}, a1[8] = {}, a2[8] = {}, a3[8] = {};
            int e = beg;
            for (; e + 4 <= end; e += 4) {
                int s0 = srcIdx[e], s1v = srcIdx[e + 1];
                int s2 = srcIdx[e + 2], s3 = srcIdx[e + 3];
                s8v v0 = *(const s8v*)(xb + (size_t)s0 * 128 + qq * 8);
                s8v v1 = *(const s8v*)(xb + (size_t)s1v * 128 + qq * 8);
                s8v v2 = *(const s8v*)(xb + (size_t)s2 * 128 + qq * 8);
                s8v v3 = *(const s8v*)(xb + (size_t)s3 * 128 + qq * 8);
                #pragma unroll
                for (int u = 0; u < 8; ++u) {
                    a0[u] += bf2f((unsigned short)v0[u]);
                    a1[u] += bf2f((unsigned short)v1[u]);
                    a2[u] += bf2f((unsigned short)v2[u]);
                    a3[u] += bf2f((unsigned short)v3[u]);
                }
            }
            for (; e < end; ++e) {
                s8v v0 = *(const s8v*)(xb + (size_t)srcIdx[e] * 128 + qq * 8);
                #pragma unroll
                for (int u = 0; u < 8; ++u) a0[u] += bf2f((unsigned short)v0[u]);
            }
            float ic = 1.0f / fmaxf((float)d, 1.0f);
            union { s8v v; unsigned short u[8]; } o;
            #pragma unroll
            for (int u = 0; u < 8; ++u)
                o.u[u] = f2bf((a0[u] + a1[u] + a2[u] + a3[u]) * ic);
            *(s8v*)&aggs[nd * 132 + qq * 8] = o.v;
        }
    }

    fx4 acc[4][4];
    fx4 z4 = {0.f, 0.f, 0.f, 0.f};
    #pragma unroll
    for (int r = 0; r < 4; ++r)
        #pragma unroll
        for (int c = 0; c < 4; ++c) acc[r][c] = z4;

    // ---- phase B: K-loop
    for (int kt = 0; kt < 8; ++kt) {
        __syncthreads();
        if (kt < 4) {
            // stage weights only; A comes from aggs
            #pragma unroll
            for (int it = 0; it < 2; ++it) {
                int i = t + it * 256;            // 0..511
                int row = i >> 2, kq = i & 3;
                s8v wv = *(const s8v*)(wB1 + (size_t)row * 256 + kt * 32 + kq * 8);
                *(s8v*)&ws[row * 40 + kq * 8] = wv;
            }
        } else {
            int kbase = (kt & 3) * 32;
            #pragma unroll
            for (int it = 0; it < 2; ++it) {
                int i = t + it * 256;
                int row = i >> 2, kq = i & 3;
                int gr = r0 + row;
                s8v v = {0, 0, 0, 0, 0, 0, 0, 0};
                if (gr < n) v = *(const s8v*)(xb + (size_t)gr * 128 + kbase + kq * 8);
                *(s8v*)&xs[row * 40 + kq * 8] = v;
                s8v wv = *(const s8v*)(wB1 + (size_t)row * 256 + kt * 32 + kq * 8);
                *(s8v*)&ws[row * 40 + kq * 8] = wv;
            }
        }
        __syncthreads();
        s8v af[4], bf[4];
        if (kt < 4) {
            #pragma unroll
            for (int r = 0; r < 4; ++r)
                af[r] = *(const s8v*)&aggs[(wr0 + r * 16 + lm) * 132 + kt * 32 + q * 8];
        } else {
            #pragma unroll
            for (int r = 0; r < 4; ++r)
                af[r] = *(const s8v*)&xs[(wr0 + r * 16 + lm) * 40 + q * 8];
        }
        #pragma unroll
        for (int c = 0; c < 4; ++c)
            bf[c] = *(const s8v*)&ws[(wc0 + c * 16 + lm) * 40 + q * 8];
        #pragma unroll
        for (int r = 0; r < 4; ++r)
            #pragma unroll
            for (int c = 0; c < 4; ++c)
                acc[r][c] = __builtin_amdgcn_mfma_f32_16x16x32_bf16(af[r], bf[c], acc[r][c], 0, 0, 0);
    }

    // ---- epilogue: bias -> row L2-norm -> scale -> bf16 store -> BN stats
    float bj[4];
    #pragma unroll
    for (int c = 0; c < 4; ++c) bj[c] = b1l[wc0 + c * 16 + lm];
    #pragma unroll
    for (int r = 0; r < 4; ++r)
        #pragma unroll
        for (int c = 0; c < 4; ++c) acc[r][c] += bj[c];

    fx4 pr[4];
    #pragma unroll
    for (int r = 0; r < 4; ++r) {
        fx4 p = acc[r][0] * acc[r][0];
        #pragma unroll
        for (int c = 1; c < 4; ++c) p += acc[r][c] * acc[r][c];
        #pragma unroll
        for (int off = 1; off <= 8; off <<= 1)
            #pragma unroll
            for (int i2 = 0; i2 < 4; ++i2) p[i2] += __shfl_xor(p[i2], off, 64);
        pr[r] = p;
    }

    __syncthreads();   // xs/ws free -> overlay reductions
    float* norm2 = (float*)xs;          // [128][2]
    float* invn  = (float*)xs + 256;    // [128]
    float* statS = (float*)ws;          // [128][2]
    float* statQ = (float*)ws + 256;    // [128][2]
    if (lm == 0) {
        #pragma unroll
        for (int r = 0; r < 4; ++r)
            #pragma unroll
            for (int i = 0; i < 4; ++i)
                norm2[(wr0 + r * 16 + q * 4 + i) * 2 + (w & 1)] = pr[r][i];
    }
    __syncthreads();
    if (t < 128) {
        float s = norm2[t * 2] + norm2[t * 2 + 1];
        invn[t] = 1.0f / fmaxf(sqrtf(s), 1e-12f);
    }
    __syncthreads();

    float cS[4] = {}, cQ[4] = {};
    #pragma unroll
    for (int r = 0; r < 4; ++r) {
        int rowb = wr0 + r * 16 + q * 4;
        fx4 iv = *(const fx4*)&invn[rowb];
        #pragma unroll
        for (int c = 0; c < 4; ++c) {
            fx4 v = acc[r][c] * iv;
            int col = wc0 + c * 16 + lm;
            #pragma unroll
            for (int i = 0; i < 4; ++i) {
                int gr = r0 + rowb + i;
                if (gr < n) {
                    s1b[(size_t)gr * 128 + col] = f2bf(v[i]);
                    cS[c] += v[i];
                    cQ[c] += v[i] * v[i];
                }
            }
        }
    }
    #pragma unroll
    for (int off = 16; off <= 32; off <<= 1)
        #pragma unroll
        for (int c = 0; c < 4; ++c) {
            cS[c] += __shfl_xor(cS[c], off, 64);
            cQ[c] += __shfl_xor(cQ[c], off, 64);
        }
    if (q == 0) {
        #pragma unroll
        for (int c = 0; c < 4; ++c) {
            int col = wc0 + c * 16 + lm;
            statS[col * 2 + (w >> 1)] = cS[c];
            statQ[col * 2 + (w >> 1)] = cQ[c];
        }
    }
    __syncthreads();
    if (t < 128) {
        atomicAdd(&stats[t],       statS[t * 2] + statS[t * 2 + 1]);
        atomicAdd(&stats[128 + t], statQ[t * 2] + statQ[t * 2 + 1]);
    }
}

// ---- BN coefficient finalize: stats -> (a, b) per channel
__global__ void k_bn_final(float* stats, const float* __restrict__ gamma,
                           const float* __restrict__ beta, int n) {
    int c = threadIdx.x;  // 128
    float s = stats[c], q = stats[128 + c];
    float fn = (float)n;
    float mean = s / fn;
    float var = q / fn - mean * mean;   // biased variance
    float istd = rsqrtf(var + 1e-5f);
    float a = gamma[c] * istd;
    float b = beta[c] - mean * a;
    stats[c] = a;
    stats[128 + c] = b;
}

// ---- GEMM2 (bf16 MFMA): h = relu(BN(s1b)) applied at staging.
// h @ [w2l|w2r]^T -> y2b[N,48] bf16 (j<47) + rbuf[N,47] f32 (j 47..93, +b2l).
__global__ __launch_bounds__(256, 3) void k_gemm2(
        const unsigned short* __restrict__ s1b, const unsigned short* __restrict__ wB2p,
        const float* __restrict__ stats, const float* __restrict__ b2l,
        unsigned short* __restrict__ y2b, float* __restrict__ rbuf, int n) {
    __shared__ __align__(16) unsigned short xs[128 * 40];
    __shared__ __align__(16) unsigned short ws[128 * 40];
    int t = threadIdx.x;
    int w = t >> 6, L = t & 63;
    int q = L >> 4, lm = L & 15;
    int wr0 = (w >> 1) * 64, wc0 = (w & 1) * 64;
    int r0 = blockIdx.x * 128;

    fx4 acc[4][4];
    fx4 z4 = {0.f, 0.f, 0.f, 0.f};
    #pragma unroll
    for (int r = 0; r < 4; ++r)
        #pragma unroll
        for (int c = 0; c < 4; ++c) acc[r][c] = z4;

    for (int kt = 0; kt < 4; ++kt) {
        int kbase = kt * 32;
        __syncthreads();
        #pragma unroll
        for (int it = 0; it < 2; ++it) {
            int i = t + it * 256;
            int row = i >> 2, kq = i & 3;
            int gr = r0 + row;
            int cb = kbase + kq * 8;
            s8v v = {0, 0, 0, 0, 0, 0, 0, 0};
            if (gr < n) {
                s8v sv = *(const s8v*)(s1b + (size_t)gr * 128 + cb);
                fx4 a0 = *(const fx4*)&stats[cb];
                fx4 a1 = *(const fx4*)&stats[cb + 4];
                fx4 b0 = *(const fx4*)&stats[128 + cb];
                fx4 b1 = *(const fx4*)&stats[128 + cb + 4];
                union { s8v v; unsigned short u[8]; } o;
                #pragma unroll
                for (int u = 0; u < 4; ++u) {
                    float h0 = fmaxf(fmaf(a0[u], bf2f((unsigned short)sv[u]), b0[u]), 0.f);
                    float h1 = fmaxf(fmaf(a1[u], bf2f((unsigned short)sv[u + 4]), b1[u]), 0.f);
                    o.u[u]     = f2bf(h0);
                    o.u[u + 4] = f2bf(h1);
                }
                v = o.v;
            }
            *(s8v*)&xs[row * 40 + kq * 8] = v;
            s8v wv = *(const s8v*)(wB2p + (size_t)row * 128 + cb);
            *(s8v*)&ws[row * 40 + kq * 8] = wv;
        }
        __syncthreads();
        s8v af[4], bf[4];
        #pragma unroll
        for (int r = 0; r < 4; ++r)
            af[r] = *(const s8v*)&xs[(wr0 + r * 16 + lm) * 40 + q * 8];
        #pragma unroll
        for (int c = 0; c < 4; ++c)
            bf[c] = *(const s8v*)&ws[(wc0 + c * 16 + lm) * 40 + q * 8];
        #pragma unroll
        for (int r = 0; r < 4; ++r)
            #pragma unroll
            for (int c = 0; c < 4; ++c)
                acc[r][c] = __builtin_amdgcn_mfma_f32_16x16x32_bf16(af[r], bf[c], acc[r][c], 0, 0, 0);
    }

    // epilogue: y2b bf16 (j<47) / rbuf fp32 + b2l (j 47..93)
    #pragma unroll
    for (int c = 0; c < 4; ++c) {
        int col = wc0 + c * 16 + lm;
        float bb = (col >= 47 && col < 94) ? b2l[col - 47] : 0.f;
        #pragma unroll
        for (int r = 0; r < 4; ++r) {
            int rowb = wr0 + r * 16 + q * 4;
            #pragma unroll
            for (int i = 0; i < 4; ++i) {
                int gr = r0 + rowb + i;
                if (gr >= n) continue;
                float v = acc[r][c][i];
                if (col < 47)      y2b[(size_t)gr * 48 + col] = f2bf(v);
                else if (col < 94) rbuf[(size_t)gr * 47 + (col - 47)] = v + bb;
            }
        }
    }
}

// ---- layer-2 gather + combine + L2-norm. One wave/node, 8-edge unroll.
__global__ __launch_bounds__(256) void k_gather2_final(
        const unsigned short* __restrict__ y2b, const float* __restrict__ rbuf,
        const int* __restrict__ rowStart, const int* __restrict__ deg,
        const int* __restrict__ srcIdx, float* __restrict__ out, int n) {
    int t = threadIdx.x;
    int lane = t & 63, w = t >> 6;
    int node = blockIdx.x * 4 + w;
    if (node >= n) return;
    int beg = rowStart[node];
    int d = deg[node];
    float v = 0.f;
    if (lane < 47) {
        int end = beg + d;
        float acc0 = 0.f, acc1 = 0.f, acc2 = 0.f, acc3 = 0.f;
        int e = beg;
        for (; e + 8 <= end; e += 8) {
            int s0 = srcIdx[e],     s1v = srcIdx[e + 1];
            int s2 = srcIdx[e + 2], s3  = srcIdx[e + 3];
            int s4 = srcIdx[e + 4], s5  = srcIdx[e + 5];
            int s6 = srcIdx[e + 6], s7  = srcIdx[e + 7];
            unsigned short l0 = y2b[(size_t)s0 * 48 + lane];
            unsigned short l1 = y2b[(size_t)s1v * 48 + lane];
            unsigned short l2 = y2b[(size_t)s2 * 48 + lane];
            unsigned short l3 = y2b[(size_t)s3 * 48 + lane];
            unsigned short l4 = y2b[(size_t)s4 * 48 + lane];
            unsigned short l5 = y2b[(size_t)s5 * 48 + lane];
            unsigned short l6 = y2b[(size_t)s6 * 48 + lane];
            unsigned short l7 = y2b[(size_t)s7 * 48 + lane];
            acc0 += bf2f(l0) + bf2f(l4);
            acc1 += bf2f(l1) + bf2f(l5);
            acc2 += bf2f(l2) + bf2f(l6);
            acc3 += bf2f(l3) + bf2f(l7);
        }
        for (; e + 4 <= end; e += 4) {
            int s0 = srcIdx[e], s1v = srcIdx[e + 1];
            int s2 = srcIdx[e + 2], s3 = srcIdx[e + 3];
            acc0 += bf2f(y2b[(size_t)s0 * 48 + lane]);
            acc1 += bf2f(y2b[(size_t)s1v * 48 + lane]);
            acc2 += bf2f(y2b[(size_t)s2 * 48 + lane]);
            acc3 += bf2f(y2b[(size_t)s3 * 48 + lane]);
        }
        for (; e < end; ++e) acc0 += bf2f(y2b[(size_t)srcIdx[e] * 48 + lane]);
        v = (acc0 + acc1 + acc2 + acc3) / fmaxf((float)d, 1.0f)
            + rbuf[(size_t)node * 47 + lane];
    }
    float ss = warp_sum64(v * v);
    float inv = 1.0f / fmaxf(sqrtf(ss), 1e-12f);
    if (lane < 47) out[(size_t)node * 47 + lane] = v * inv;
}

extern "C" void kernel_launch(void* const* d_in, const int* in_sizes, int n_in,
                              void* d_out, int out_size, void* d_ws, size_t ws_size,
                              hipStream_t stream) {
    const float* x     = (const float*)d_in[0];
    const int*   ei    = (const int*)d_in[1];
    const float* w1l   = (const float*)d_in[2];
    const float* b1l   = (const float*)d_in[3];
    const float* w1r   = (const float*)d_in[4];
    const float* gamma = (const float*)d_in[5];
    const float* beta  = (const float*)d_in[6];
    const float* w2l   = (const float*)d_in[7];
    const float* b2l   = (const float*)d_in[8];
    const float* w2r   = (const float*)d_in[9];
    float* out = (float*)d_out;

    int n  = in_sizes[0] / 128;   // 100000
    int nE = in_sizes[1] / 2;     // 800000

    int NB  = (n + 255) >> 8;                    // 391 buckets
    int nCh = (nE + CSR_CHUNK - 1) / CSR_CHUNK;  // 98 chunks

    // ---- workspace layout ----
    // deg[n](int) | stats[256](f32) | rowStart[n] | meta[n] | srcIdx[nE]
    // | xb[128n bf16] | spare[128n bf16] | s1b[128n bf16] | wB1 | wB2p
    // meta: counts[nCh*512] then bucketStart[NB+1] at +60000.
    // pairs[nE] overlays s1b (dead until gemm1).
    // y2b[48n bf16] + rbuf[47n f32] overlay xb (dead after gemm1).
    int* deg       = (int*)d_ws;
    float* stats   = (float*)(deg + n);
    int* rowStart  = (int*)(stats + 256);
    int* meta      = rowStart + n;
    int* srcIdx    = meta + n;
    unsigned short* xb   = (unsigned short*)(srcIdx + nE);
    unsigned short* s1b  = xb + (size_t)n * 256;    // skip spare region
    unsigned short* wB1  = s1b + (size_t)n * 128;
    unsigned short* wB2p = wB1 + 32768;
    int* counts      = meta;
    int* bucketStart = meta + 60000;
    int* pairs       = (int*)s1b;             // packed (src<<8)|(dst&255)
    unsigned short* y2b = xb;                 // stride 48 shorts
    float* rbuf = (float*)(y2b + (size_t)n * 48);

    int prepTotal = n * 16 + 32768 + 16384 + 256;

    k_prep<<<(prepTotal + 255) / 256, 256, 0, stream>>>(
        x, w1l, w1r, w2l, w2r, xb, wB1, wB2p, stats, n);
    // CSR build (bucketed counting sort)
    k_bcount<<<nCh, 256, 0, stream>>>(ei, counts, nE);
    k_bmeta<<<1, 256, 0, stream>>>(counts, bucketStart, nE, nCh, NB);
    k_bfill<<<nCh, 256, 0, stream>>>(ei, counts, pairs, nE);
    k_csr<<<NB, 256, 0, stream>>>(pairs, bucketStart, deg, rowStart, srcIdx, n);
    // layer 1 (gather fused into gemm)
    k_gemm1<<<(n + 127) / 128, 256, 0, stream>>>(
        xb, wB1, b1l, rowStart, deg, srcIdx, s1b, stats, n);
    k_bn_final<<<1, 128, 0, stream>>>(stats, gamma, beta, n);
    // layer 2
    k_gemm2<<<(n + 127) / 128, 256, 0, stream>>>(s1b, wB2p, stats, b2l, y2b, rbuf, n);
    k_gather2_final<<<(n + 3) / 4, 256, 0, stream>>>(y2b, rbuf, rowStart, deg, srcIdx, out, n);
}

// Round 10
// 333.440 us; speedup vs baseline: 1.0780x; 1.0780x over previous
//
#include <hip/hip_runtime.h>
#include <cstdint>

// GNN: 2-layer GraphSAGE (mean aggr, L2-normalize) + BatchNorm(train) + ReLU.
// N=100000 nodes, E=800000 edges, C: 128 -> 128 -> 47.
//
// Round 10: REVERT R9's gather1+gemm1 fusion (regressed: phases correlate
// across blocks at kernel start -> no overlap, occupancy 15.6%). Back to R8
// split kernels; instead cut launch count 11 -> 8:
//  - k_bcount merged into k_prep (block-uniform branch, extra blocks).
//  - k_bn_final merged into k_gemm2 (per-block BN-coeff recompute in LDS).
//  - stats zeroing stays in k_prep (no memset launch).
// CSR build: bucketed counting sort (R8). GEMMs: bf16 MFMA 16x16x32
// (fp32 VALU ceiling measured 111 TF in R5). gather2: 8-edge unroll (R9 win).

typedef __attribute__((ext_vector_type(8))) short s8v;
typedef __attribute__((ext_vector_type(4))) float fx4;

#define CSR_CHUNK 8192
#define CSR_SH 8            // 256 nodes per bucket
#define CSR_NBPAD 512       // padded bucket count (NB = ceil(n/256) = 391)
#define CSR_BUFCAP 3072     // LDS srcbuf cap per bucket (mean 2046, +20 sigma)

static __device__ __forceinline__ float bf2f(unsigned short h) {
    union { unsigned int u; float f; } c; c.u = (unsigned int)h << 16; return c.f;
}
static __device__ __forceinline__ unsigned short f2bf(float f) {
    union { float f; unsigned int u; } c; c.f = f;
    unsigned int u = c.u;
    return (unsigned short)((u + 0x7FFF + ((u >> 16) & 1)) >> 16);   // RNE
}

static __device__ __forceinline__ float warp_sum64(float v) {
    #pragma unroll
    for (int off = 32; off > 0; off >>= 1) v += __shfl_xor(v, off, 64);
    return v;
}

// ---- merged prep: x->bf16 | weight casts | stats zero | bcount histograms.
// Blocks [0, prepBlocks): elementwise ranges. Blocks [prepBlocks, +nCh):
// per-chunk dst-bucket histograms (R8's k_bcount).
__global__ __launch_bounds__(256) void k_prep(
        const float* __restrict__ x, const float* __restrict__ w1l,
        const float* __restrict__ w1r, const float* __restrict__ w2l,
        const float* __restrict__ w2r, const int* __restrict__ ei,
        unsigned short* __restrict__ xb, unsigned short* __restrict__ wB1,
        unsigned short* __restrict__ wB2p, float* __restrict__ stats,
        int* __restrict__ counts, int n, int nE, int prepBlocks) {
    __shared__ int hist[CSR_NBPAD];
    int t = threadIdx.x;
    if ((int)blockIdx.x >= prepBlocks) {
        int chunk = blockIdx.x - prepBlocks;
        hist[t] = 0; hist[t + 256] = 0;
        __syncthreads();
        int e0 = chunk * CSR_CHUNK;
        int e1 = min(e0 + CSR_CHUNK, nE);
        for (int e = e0 + t; e < e1; e += 256)
            atomicAdd(&hist[ei[nE + e] >> CSR_SH], 1);
        __syncthreads();
        counts[chunk * CSR_NBPAD + t] = hist[t];
        counts[chunk * CSR_NBPAD + t + 256] = hist[t + 256];
        return;
    }
    int idx = blockIdx.x * 256 + t;
    int nx = n * 16;
    if (idx < nx) {
        float4 a = ((const float4*)x)[idx * 2];
        float4 b = ((const float4*)x)[idx * 2 + 1];
        union { s8v v; unsigned short u[8]; } o;
        o.u[0] = f2bf(a.x); o.u[1] = f2bf(a.y); o.u[2] = f2bf(a.z); o.u[3] = f2bf(a.w);
        o.u[4] = f2bf(b.x); o.u[5] = f2bf(b.y); o.u[6] = f2bf(b.z); o.u[7] = f2bf(b.w);
        ((s8v*)xb)[idx] = o.v;
        return;
    }
    idx -= nx;
    if (idx < 32768) {
        int j = idx >> 8, k = idx & 255;
        float v = (k < 128) ? w1l[j * 128 + k] : w1r[j * 128 + (k - 128)];
        wB1[idx] = f2bf(v);
        return;
    }
    idx -= 32768;
    if (idx < 16384) {
        int j = idx >> 7, k = idx & 127;
        float v = 0.f;
        if (j < 47)      v = w2l[j * 128 + k];
        else if (j < 94) v = w2r[(j - 47) * 128 + k];
        wB2p[idx] = f2bf(v);
        return;
    }
    idx -= 16384;
    if (idx < 256) stats[idx] = 0.f;
}

// ---- CSR build: bucketed counting sort -------------------------------
__global__ __launch_bounds__(256) void k_bmeta(
        int* __restrict__ counts, int* __restrict__ bucketStart,
        int nE, int nCh, int NB) {
    __shared__ int tot[CSR_NBPAD], sh[256], bs[CSR_NBPAD];
    int t = threadIdx.x;
    for (int b = t; b < CSR_NBPAD; b += 256) {
        int s = 0;
        for (int c = 0; c < nCh; ++c) s += counts[c * CSR_NBPAD + b];
        tot[b] = s;
    }
    __syncthreads();
    int pairSum = tot[2 * t] + tot[2 * t + 1];
    sh[t] = pairSum;
    __syncthreads();
    for (int off = 1; off < 256; off <<= 1) {
        int add = (t >= off) ? sh[t - off] : 0;
        __syncthreads();
        sh[t] += add;
        __syncthreads();
    }
    int excl = sh[t] - pairSum;
    bs[2 * t] = excl;
    bs[2 * t + 1] = excl + tot[2 * t];
    __syncthreads();
    for (int b = t; b <= NB; b += 256) bucketStart[b] = bs[b];
    for (int b = t; b < CSR_NBPAD; b += 256) {
        int run = bs[b];
        for (int c = 0; c < nCh; ++c) {
            int v = counts[c * CSR_NBPAD + b];
            counts[c * CSR_NBPAD + b] = run;
            run += v;
        }
    }
}

__global__ __launch_bounds__(256) void k_bfill(
        const int* __restrict__ ei, const int* __restrict__ counts,
        int* __restrict__ pairs, int nE) {
    __shared__ int cur[CSR_NBPAD];
    int t = threadIdx.x;
    cur[t] = counts[blockIdx.x * CSR_NBPAD + t];
    cur[t + 256] = counts[blockIdx.x * CSR_NBPAD + t + 256];
    __syncthreads();
    int e0 = blockIdx.x * CSR_CHUNK;
    int e1 = min(e0 + CSR_CHUNK, nE);
    for (int e = e0 + t; e < e1; e += 256) {
        int s = ei[e];
        int d = ei[nE + e];
        int p = atomicAdd(&cur[d >> CSR_SH], 1);
        pairs[p] = (s << 8) | (d & 255);
    }
}

__global__ __launch_bounds__(256) void k_csr(
        const int* __restrict__ pairs, const int* __restrict__ bucketStart,
        int* __restrict__ deg, int* __restrict__ rowStart,
        int* __restrict__ srcIdx, int n) {
    __shared__ int cnt[256], scn[256], cur[256];
    __shared__ int buf[CSR_BUFCAP];
    int t = threadIdx.x;
    int bkt = blockIdx.x;
    int eBeg = bucketStart[bkt], eEnd = bucketStart[bkt + 1];
    int node0 = bkt << CSR_SH;
    cnt[t] = 0;
    __syncthreads();
    for (int e = eBeg + t; e < eEnd; e += 256)
        atomicAdd(&cnt[pairs[e] & 255], 1);
    __syncthreads();
    int myc = cnt[t];
    scn[t] = myc;
    __syncthreads();
    for (int off = 1; off < 256; off <<= 1) {
        int add = (t >= off) ? scn[t - off] : 0;
        __syncthreads();
        scn[t] += add;
        __syncthreads();
    }
    int excl = scn[t] - myc;
    cur[t] = excl;
    int node = node0 + t;
    if (node < n) { deg[node] = myc; rowStart[node] = eBeg + excl; }
    __syncthreads();
    for (int e = eBeg + t; e < eEnd; e += 256) {
        int pk = pairs[e];
        int p = atomicAdd(&cur[pk & 255], 1);
        int src = pk >> 8;
        if (p < CSR_BUFCAP) buf[p] = src;
        else srcIdx[eBeg + p] = src;   // statistically never at this size
    }
    __syncthreads();
    int m = min(eEnd - eBeg, CSR_BUFCAP);
    for (int i = t; i < m; i += 256) srcIdx[eBeg + i] = buf[i];
}

// ---- layer-1 gather (bf16): 16 lanes/node, lane owns 8 ch; 4-edge unroll.
__global__ __launch_bounds__(256) void k_gather1(
        const unsigned short* __restrict__ xb, const int* __restrict__ rowStart,
        const int* __restrict__ deg, const int* __restrict__ srcIdx,
        unsigned short* __restrict__ aggb, int n) {
    int t = threadIdx.x;
    int q = t & 15, grp = t >> 4;
    int node = blockIdx.x * 16 + grp;
    if (node >= n) return;
    int beg = rowStart[node];
    int d = deg[node];
    int end = beg + d;
    float a0[8] = {}, a1[8] = {}, a2[8] = {}, a3[8] = {};
    int e = beg;
    for (; e + 4 <= end; e += 4) {
        int s0 = srcIdx[e], s1v = srcIdx[e + 1], s2 = srcIdx[e + 2], s3 = srcIdx[e + 3];
        s8v v0 = *(const s8v*)(xb + (size_t)s0 * 128 + q * 8);
        s8v v1 = *(const s8v*)(xb + (size_t)s1v * 128 + q * 8);
        s8v v2 = *(const s8v*)(xb + (size_t)s2 * 128 + q * 8);
        s8v v3 = *(const s8v*)(xb + (size_t)s3 * 128 + q * 8);
        #pragma unroll
        for (int u = 0; u < 8; ++u) {
            a0[u] += bf2f((unsigned short)v0[u]);
            a1[u] += bf2f((unsigned short)v1[u]);
            a2[u] += bf2f((unsigned short)v2[u]);
            a3[u] += bf2f((unsigned short)v3[u]);
        }
    }
    for (; e < end; ++e) {
        s8v v0 = *(const s8v*)(xb + (size_t)srcIdx[e] * 128 + q * 8);
        #pragma unroll
        for (int u = 0; u < 8; ++u) a0[u] += bf2f((unsigned short)v0[u]);
    }
    float ic = 1.0f / fmaxf((float)d, 1.0f);
    union { s8v v; unsigned short u[8]; } o;
    #pragma unroll
    for (int u = 0; u < 8; ++u)
        o.u[u] = f2bf((a0[u] + a1[u] + a2[u] + a3[u]) * ic);
    *(s8v*)(aggb + (size_t)node * 128 + q * 8) = o.v;
}

// ---- GEMM1 (bf16 MFMA): block 128x128, K=256 (aggb then xb).
// s1b = bf16( L2norm_rows( aggm @ w1l^T + b1l + x @ w1r^T ) );
// accumulates per-channel sum/sumsq of s1 into stats (1 atomic pair/ch/block).
__global__ __launch_bounds__(256, 3) void k_gemm1(
        const unsigned short* __restrict__ xb, const unsigned short* __restrict__ aggb,
        const unsigned short* __restrict__ wB1, const float* __restrict__ b1l,
        unsigned short* __restrict__ s1b, float* __restrict__ stats, int n) {
    __shared__ __align__(16) unsigned short xs[128 * 40];   // [row][k] stride 40
    __shared__ __align__(16) unsigned short ws[128 * 40];   // [j][k]   stride 40
    int t = threadIdx.x;
    int w = t >> 6, L = t & 63;
    int q = L >> 4, lm = L & 15;
    int wr0 = (w >> 1) * 64;     // wave row base
    int wc0 = (w & 1) * 64;      // wave col base
    int r0 = blockIdx.x * 128;

    fx4 acc[4][4];
    fx4 z4 = {0.f, 0.f, 0.f, 0.f};
    #pragma unroll
    for (int r = 0; r < 4; ++r)
        #pragma unroll
        for (int c = 0; c < 4; ++c) acc[r][c] = z4;

    for (int kt = 0; kt < 8; ++kt) {
        const unsigned short* src = (kt < 4) ? aggb : xb;
        int kbase = (kt & 3) * 32;
        __syncthreads();
        #pragma unroll
        for (int it = 0; it < 2; ++it) {
            int i = t + it * 256;            // 0..511
            int row = i >> 2, kq = i & 3;
            int gr = r0 + row;
            s8v v = {0, 0, 0, 0, 0, 0, 0, 0};
            if (gr < n) v = *(const s8v*)(src + (size_t)gr * 128 + kbase + kq * 8);
            *(s8v*)&xs[row * 40 + kq * 8] = v;
            s8v wv = *(const s8v*)(wB1 + (size_t)row * 256 + kt * 32 + kq * 8);
            *(s8v*)&ws[row * 40 + kq * 8] = wv;
        }
        __syncthreads();
        s8v af[4], bf[4];
        #pragma unroll
        for (int r = 0; r < 4; ++r)
            af[r] = *(const s8v*)&xs[(wr0 + r * 16 + lm) * 40 + q * 8];
        #pragma unroll
        for (int c = 0; c < 4; ++c)
            bf[c] = *(const s8v*)&ws[(wc0 + c * 16 + lm) * 40 + q * 8];
        #pragma unroll
        for (int r = 0; r < 4; ++r)
            #pragma unroll
            for (int c = 0; c < 4; ++c)
                acc[r][c] = __builtin_amdgcn_mfma_f32_16x16x32_bf16(af[r], bf[c], acc[r][c], 0, 0, 0);
    }

    // ---- epilogue: bias -> row L2-norm -> scale -> bf16 store -> BN stats
    float bj[4];
    #pragma unroll
    for (int c = 0; c < 4; ++c) bj[c] = b1l[wc0 + c * 16 + lm];
    #pragma unroll
    for (int r = 0; r < 4; ++r)
        #pragma unroll
        for (int c = 0; c < 4; ++c) acc[r][c] += bj[c];

    fx4 pr[4];
    #pragma unroll
    for (int r = 0; r < 4; ++r) {
        fx4 p = acc[r][0] * acc[r][0];
        #pragma unroll
        for (int c = 1; c < 4; ++c) p += acc[r][c] * acc[r][c];
        #pragma unroll
        for (int off = 1; off <= 8; off <<= 1)
            #pragma unroll
            for (int i2 = 0; i2 < 4; ++i2) p[i2] += __shfl_xor(p[i2], off, 64);
        pr[r] = p;
    }

    __syncthreads();   // xs/ws free -> overlay reductions
    float* norm2 = (float*)xs;          // [128][2]
    float* invn  = (float*)xs + 256;    // [128]
    float* statS = (float*)ws;          // [128][2]
    float* statQ = (float*)ws + 256;    // [128][2]
    if (lm == 0) {
        #pragma unroll
        for (int r = 0; r < 4; ++r)
            #pragma unroll
            for (int i = 0; i < 4; ++i)
                norm2[(wr0 + r * 16 + q * 4 + i) * 2 + (w & 1)] = pr[r][i];
    }
    __syncthreads();
    if (t < 128) {
        float s = norm2[t * 2] + norm2[t * 2 + 1];
        invn[t] = 1.0f / fmaxf(sqrtf(s), 1e-12f);
    }
    __syncthreads();

    float cS[4] = {}, cQ[4] = {};
    #pragma unroll
    for (int r = 0; r < 4; ++r) {
        int rowb = wr0 + r * 16 + q * 4;
        fx4 iv = *(const fx4*)&invn[rowb];
        #pragma unroll
        for (int c = 0; c < 4; ++c) {
            fx4 v = acc[r][c] * iv;
            int col = wc0 + c * 16 + lm;
            #pragma unroll
            for (int i = 0; i < 4; ++i) {
                int gr = r0 + rowb + i;
                if (gr < n) {
                    s1b[(size_t)gr * 128 + col] = f2bf(v[i]);
                    cS[c] += v[i];
                    cQ[c] += v[i] * v[i];
                }
            }
        }
    }
    #pragma unroll
    for (int off = 16; off <= 32; off <<= 1)
        #pragma unroll
        for (int c = 0; c < 4; ++c) {
            cS[c] += __shfl_xor(cS[c], off, 64);
            cQ[c] += __shfl_xor(cQ[c], off, 64);
        }
    if (q == 0) {
        #pragma unroll
        for (int c = 0; c < 4; ++c) {
            int col = wc0 + c * 16 + lm;
            statS[col * 2 + (w >> 1)] = cS[c];
            statQ[col * 2 + (w >> 1)] = cQ[c];
        }
    }
    __syncthreads();
    if (t < 128) {
        atomicAdd(&stats[t],       statS[t * 2] + statS[t * 2 + 1]);
        atomicAdd(&stats[128 + t], statQ[t * 2] + statQ[t * 2 + 1]);
    }
}

// ---- GEMM2 (bf16 MFMA) with inline BN finalize. Each block recomputes the
// 128 (a,b) coefficients from raw stats (gemm1's atomics are visible across
// the kernel boundary). h = relu(BN(s1b)) applied at staging.
// h @ [w2l|w2r]^T -> y2b[N,48] bf16 (j<47) + rbuf[N,47] f32 (j 47..93, +b2l).
__global__ __launch_bounds__(256, 3) void k_gemm2(
        const unsigned short* __restrict__ s1b, const unsigned short* __restrict__ wB2p,
        const float* __restrict__ stats, const float* __restrict__ gamma,
        const float* __restrict__ beta, const float* __restrict__ b2l,
        unsigned short* __restrict__ y2b, float* __restrict__ rbuf, int n) {
    __shared__ __align__(16) unsigned short xs[128 * 40];
    __shared__ __align__(16) unsigned short ws[128 * 40];
    __shared__ __align__(16) float abuf[128];
    __shared__ __align__(16) float bbuf[128];
    int t = threadIdx.x;
    int w = t >> 6, L = t & 63;
    int q = L >> 4, lm = L & 15;
    int wr0 = (w >> 1) * 64, wc0 = (w & 1) * 64;
    int r0 = blockIdx.x * 128;

    if (t < 128) {
        float s = stats[t], qv = stats[128 + t];
        float fn = (float)n;
        float mean = s / fn;
        float var = qv / fn - mean * mean;   // biased variance
        float istd = rsqrtf(var + 1e-5f);
        float a = gamma[t] * istd;
        abuf[t] = a;
        bbuf[t] = beta[t] - mean * a;
    }
    __syncthreads();

    fx4 acc[4][4];
    fx4 z4 = {0.f, 0.f, 0.f, 0.f};
    #pragma unroll
    for (int r = 0; r < 4; ++r)
        #pragma unroll
        for (int c = 0; c < 4; ++c) acc[r][c] = z4;

    for (int kt = 0; kt < 4; ++kt) {
        int kbase = kt * 32;
        __syncthreads();
        #pragma unroll
        for (int it = 0; it < 2; ++it) {
            int i = t + it * 256;
            int row = i >> 2, kq = i & 3;
            int gr = r0 + row;
            int cb = kbase + kq * 8;
            s8v v = {0, 0, 0, 0, 0, 0, 0, 0};
            if (gr < n) {
                s8v sv = *(const s8v*)(s1b + (size_t)gr * 128 + cb);
                fx4 a0 = *(const fx4*)&abuf[cb];
                fx4 a1 = *(const fx4*)&abuf[cb + 4];
                fx4 b0 = *(const fx4*)&bbuf[cb];
                fx4 b1 = *(const fx4*)&bbuf[cb + 4];
                union { s8v v; unsigned short u[8]; } o;
                #pragma unroll
                for (int u = 0; u < 4; ++u) {
                    float h0 = fmaxf(fmaf(a0[u], bf2f((unsigned short)sv[u]), b0[u]), 0.f);
                    float h1 = fmaxf(fmaf(a1[u], bf2f((unsigned short)sv[u + 4]), b1[u]), 0.f);
                    o.u[u]     = f2bf(h0);
                    o.u[u + 4] = f2bf(h1);
                }
                v = o.v;
            }
            *(s8v*)&xs[row * 40 + kq * 8] = v;
            s8v wv = *(const s8v*)(wB2p + (size_t)row * 128 + cb);
            *(s8v*)&ws[row * 40 + kq * 8] = wv;
        }
        __syncthreads();
        s8v af[4], bf[4];
        #pragma unroll
        for (int r = 0; r < 4; ++r)
            af[r] = *(const s8v*)&xs[(wr0 + r * 16 + lm) * 40 + q * 8];
        #pragma unroll
        for (int c = 0; c < 4; ++c)
            bf[c] = *(const s8v*)&ws[(wc0 + c * 16 + lm) * 40 + q * 8];
        #pragma unroll
        for (int r = 0; r < 4; ++r)
            #pragma unroll
            for (int c = 0; c < 4; ++c)
                acc[r][c] = __builtin_amdgcn_mfma_f32_16x16x32_bf16(af[r], bf[c], acc[r][c], 0, 0, 0);
    }

    // epilogue: y2b bf16 (j<47) / rbuf fp32 + b2l (j 47..93)
    #pragma unroll
    for (int c = 0; c < 4; ++c) {
        int col = wc0 + c * 16 + lm;
        float bb = (col >= 47 && col < 94) ? b2l[col - 47] : 0.f;
        #pragma unroll
        for (int r = 0; r < 4; ++r) {
            int rowb = wr0 + r * 16 + q * 4;
            #pragma unroll
            for (int i = 0; i < 4; ++i) {
                int gr = r0 + rowb + i;
                if (gr >= n) continue;
                float v = acc[r][c][i];
                if (col < 47)      y2b[(size_t)gr * 48 + col] = f2bf(v);
                else if (col < 94) rbuf[(size_t)gr * 47 + (col - 47)] = v + bb;
            }
        }
    }
}

// ---- layer-2 gather + combine + L2-norm. One wave/node, 8-edge unroll.
__global__ __launch_bounds__(256) void k_gather2_final(
        const unsigned short* __restrict__ y2b, const float* __restrict__ rbuf,
        const int* __restrict__ rowStart, const int* __restrict__ deg,
        const int* __restrict__ srcIdx, float* __restrict__ out, int n) {
    int t = threadIdx.x;
    int lane = t & 63, w = t >> 6;
    int node = blockIdx.x * 4 + w;
    if (node >= n) return;
    int beg = rowStart[node];
    int d = deg[node];
    float v = 0.f;
    if (lane < 47) {
        int end = beg + d;
        float acc0 = 0.f, acc1 = 0.f, acc2 = 0.f, acc3 = 0.f;
        int e = beg;
        for (; e + 8 <= end; e += 8) {
            int s0 = srcIdx[e],     s1v = srcIdx[e + 1];
            int s2 = srcIdx[e + 2], s3  = srcIdx[e + 3];
            int s4 = srcIdx[e + 4], s5  = srcIdx[e + 5];
            int s6 = srcIdx[e + 6], s7  = srcIdx[e + 7];
            unsigned short l0 = y2b[(size_t)s0 * 48 + lane];
            unsigned short l1 = y2b[(size_t)s1v * 48 + lane];
            unsigned short l2 = y2b[(size_t)s2 * 48 + lane];
            unsigned short l3 = y2b[(size_t)s3 * 48 + lane];
            unsigned short l4 = y2b[(size_t)s4 * 48 + lane];
            unsigned short l5 = y2b[(size_t)s5 * 48 + lane];
            unsigned short l6 = y2b[(size_t)s6 * 48 + lane];
            unsigned short l7 = y2b[(size_t)s7 * 48 + lane];
            acc0 += bf2f(l0) + bf2f(l4);
            acc1 += bf2f(l1) + bf2f(l5);
            acc2 += bf2f(l2) + bf2f(l6);
            acc3 += bf2f(l3) + bf2f(l7);
        }
        for (; e + 4 <= end; e += 4) {
            int s0 = srcIdx[e], s1v = srcIdx[e + 1];
            int s2 = srcIdx[e + 2], s3 = srcIdx[e + 3];
            acc0 += bf2f(y2b[(size_t)s0 * 48 + lane]);
            acc1 += bf2f(y2b[(size_t)s1v * 48 + lane]);
            acc2 += bf2f(y2b[(size_t)s2 * 48 + lane]);
            acc3 += bf2f(y2b[(size_t)s3 * 48 + lane]);
        }
        for (; e < end; ++e) acc0 += bf2f(y2b[(size_t)srcIdx[e] * 48 + lane]);
        v = (acc0 + acc1 + acc2 + acc3) / fmaxf((float)d, 1.0f)
            + rbuf[(size_t)node * 47 + lane];
    }
    float ss = warp_sum64(v * v);
    float inv = 1.0f / fmaxf(sqrtf(ss), 1e-12f);
    if (lane < 47) out[(size_t)node * 47 + lane] = v * inv;
}

extern "C" void kernel_launch(void* const* d_in, const int* in_sizes, int n_in,
                              void* d_out, int out_size, void* d_ws, size_t ws_size,
                              hipStream_t stream) {
    const float* x     = (const float*)d_in[0];
    const int*   ei    = (const int*)d_in[1];
    const float* w1l   = (const float*)d_in[2];
    const float* b1l   = (const float*)d_in[3];
    const float* w1r   = (const float*)d_in[4];
    const float* gamma = (const float*)d_in[5];
    const float* beta  = (const float*)d_in[6];
    const float* w2l   = (const float*)d_in[7];
    const float* b2l   = (const float*)d_in[8];
    const float* w2r   = (const float*)d_in[9];
    float* out = (float*)d_out;

    int n  = in_sizes[0] / 128;   // 100000
    int nE = in_sizes[1] / 2;     // 800000

    int NB  = (n + 255) >> 8;                    // 391 buckets
    int nCh = (nE + CSR_CHUNK - 1) / CSR_CHUNK;  // 98 chunks

    // ---- workspace layout (R8) ----
    // deg[n](int) | stats[256](f32) | rowStart[n] | meta[n] | srcIdx[nE]
    // | xb[128n bf16] | aggb[128n bf16] | s1b[128n bf16] | wB1 | wB2p
    // meta: counts[nCh*512] then bucketStart[NB+1] at +60000.
    // pairs[nE] overlays s1b (dead until gemm1).
    // y2b[48n bf16] + rbuf[47n f32] overlay xb+aggb (dead after gemm1).
    int* deg       = (int*)d_ws;
    float* stats   = (float*)(deg + n);
    int* rowStart  = (int*)(stats + 256);
    int* meta      = rowStart + n;
    int* srcIdx    = meta + n;
    unsigned short* xb   = (unsigned short*)(srcIdx + nE);
    unsigned short* aggb = xb + (size_t)n * 128;
    unsigned short* s1b  = aggb + (size_t)n * 128;
    unsigned short* wB1  = s1b + (size_t)n * 128;
    unsigned short* wB2p = wB1 + 32768;
    int* counts      = meta;
    int* bucketStart = meta + 60000;
    int* pairs       = (int*)s1b;             // packed (src<<8)|(dst&255)
    unsigned short* y2b = xb;                 // stride 48 shorts
    float* rbuf = (float*)(y2b + (size_t)n * 48);

    int prepTotal  = n * 16 + 32768 + 16384 + 256;
    int prepBlocks = (prepTotal + 255) / 256;

    // 1: prep (xcast | weight casts | stats zero | bcount histograms)
    k_prep<<<prepBlocks + nCh, 256, 0, stream>>>(
        x, w1l, w1r, w2l, w2r, ei, xb, wB1, wB2p, stats, counts, n, nE, prepBlocks);
    // 2-4: CSR build (bucketed counting sort)
    k_bmeta<<<1, 256, 0, stream>>>(counts, bucketStart, nE, nCh, NB);
    k_bfill<<<nCh, 256, 0, stream>>>(ei, counts, pairs, nE);
    k_csr<<<NB, 256, 0, stream>>>(pairs, bucketStart, deg, rowStart, srcIdx, n);
    // 5-6: layer 1
    k_gather1<<<(n + 15) / 16, 256, 0, stream>>>(xb, rowStart, deg, srcIdx, aggb, n);
    k_gemm1<<<(n + 127) / 128, 256, 0, stream>>>(xb, aggb, wB1, b1l, s1b, stats, n);
    // 7-8: layer 2 (BN finalize inlined in gemm2)
    k_gemm2<<<(n + 127) / 128, 256, 0, stream>>>(
        s1b, wB2p, stats, gamma, beta, b2l, y2b, rbuf, n);
    k_gather2_final<<<(n + 3) / 4, 256, 0, stream>>>(y2b, rbuf, rowStart, deg, srcIdx, out, n);
}